// Round 1
// baseline (374.575 us; speedup 1.0000x reference)
//
#include <hip/hip_runtime.h>
#include <hip/hip_bf16.h>

#define NB 32
#define NS 2048
#define ND 1024
#define NA 1024
#define MASK_NEG 1e30f

typedef __attribute__((ext_vector_type(4))) float f32x4;
typedef __attribute__((ext_vector_type(8))) __bf16 bf16x8;

// ---------------- Stage 0: zero the scores accumulator ----------------
__global__ void zero_f32(float* __restrict__ p, int n) {
  int i = blockIdx.x * 256 + threadIdx.x;
  if (i < n) p[i] = 0.f;
}

// ---------------- Stage A: w1q[b,a] = query[b,:] . W1[a,:]  (fp32) ----------------
__global__ __launch_bounds__(256) void w1q_kernel(const float* __restrict__ q,
                                                  const float* __restrict__ W1,
                                                  float* __restrict__ w1q) {
  const int b = blockIdx.y;
  const int a0 = blockIdx.x * 64;
  const int t = threadIdx.x;
  const int al = t >> 2;    // 0..63 local a
  const int part = t & 3;   // quarter of d
  const float* wrow = W1 + (size_t)(a0 + al) * ND + part * 256;
  const float* qrow = q + (size_t)b * ND + part * 256;
  float sum = 0.f;
#pragma unroll 8
  for (int i = 0; i < 256; i += 4) {
    float4 w = *reinterpret_cast<const float4*>(wrow + i);
    float4 x = *reinterpret_cast<const float4*>(qrow + i);
    sum += w.x * x.x + w.y * x.y + w.z * x.z + w.w * x.w;
  }
  __shared__ float red[256];
  red[t] = sum;
  __syncthreads();
  if (t < 64) {
    w1q[(size_t)b * NA + a0 + t] = red[t * 4] + red[t * 4 + 1] + red[t * 4 + 2] + red[t * 4 + 3];
  }
}

// ---------------- Stage B: fused scores GEMM ----------------
// scores[bs] += sum_{a in tile} v[a] * tanh(w1q[b,a] + keys[bs,:] . W2[a,:])
#define BM 128
#define BN 128
#define BK 32
#define LDK 40  // padded LDS row stride (bf16 elems): 80B, 16B-aligned, 2-way bank alias only

__global__ __launch_bounds__(256) void score_gemm(const float* __restrict__ keys,
                                                  const float* __restrict__ W2,
                                                  const float* __restrict__ w1q,
                                                  const float* __restrict__ vvec,
                                                  float* __restrict__ scores) {
  __shared__ __bf16 ldsA[BM * LDK];
  __shared__ __bf16 ldsB[BN * LDK];
  __shared__ float sm_w1q[BN];
  __shared__ float sm_v[BN];

  const int t = threadIdx.x;
  const int ntile = blockIdx.x;   // 0..7   (a-tiles)
  const int mtile = blockIdx.y;   // 0..511 (bs-tiles)
  const int bs0 = mtile * BM;
  const int b = bs0 / NS;         // 128 | 2048, so one b per block
  const int a0 = ntile * BN;

  if (t < BN) {
    sm_w1q[t] = w1q[(size_t)b * NA + a0 + t];
    sm_v[t] = vvec[a0 + t];
  }

  const int lane = t & 63;
  const int lrow = lane & 15;   // MFMA fragment row/col
  const int ko = lane >> 4;     // k-octet
  const int wid = t >> 6;
  const int wr = wid >> 1;      // wave row (2x2 over 128x128 -> each wave 64x64)
  const int wc = wid & 1;

  // staging: thread t handles row sr, 16-float half sh
  const int sr = t >> 1;
  const int sh = t & 1;
  const float* gA = keys + (size_t)(bs0 + sr) * ND + sh * 16;
  const float* gB = W2 + (size_t)(a0 + sr) * ND + sh * 16;
  __bf16* wA = &ldsA[sr * LDK + sh * 16];
  __bf16* wB = &ldsB[sr * LDK + sh * 16];

  f32x4 acc[4][4];
#pragma unroll
  for (int i = 0; i < 4; ++i)
#pragma unroll
    for (int j = 0; j < 4; ++j) acc[i][j] = f32x4{0.f, 0.f, 0.f, 0.f};

  for (int k0 = 0; k0 < ND; k0 += BK) {
    float fa[16], fb[16];
#pragma unroll
    for (int i = 0; i < 4; ++i) {
      float4 ta = *reinterpret_cast<const float4*>(gA + k0 + i * 4);
      float4 tb = *reinterpret_cast<const float4*>(gB + k0 + i * 4);
      fa[i * 4 + 0] = ta.x; fa[i * 4 + 1] = ta.y; fa[i * 4 + 2] = ta.z; fa[i * 4 + 3] = ta.w;
      fb[i * 4 + 0] = tb.x; fb[i * 4 + 1] = tb.y; fb[i * 4 + 2] = tb.z; fb[i * 4 + 3] = tb.w;
    }
    __syncthreads();  // previous iteration's fragment reads complete
    bf16x8 pa0, pa1, pb0, pb1;
#pragma unroll
    for (int j = 0; j < 8; ++j) {
      pa0[j] = (__bf16)fa[j];     pa1[j] = (__bf16)fa[8 + j];
      pb0[j] = (__bf16)fb[j];     pb1[j] = (__bf16)fb[8 + j];
    }
    *reinterpret_cast<bf16x8*>(wA) = pa0;
    *reinterpret_cast<bf16x8*>(wA + 8) = pa1;
    *reinterpret_cast<bf16x8*>(wB) = pb0;
    *reinterpret_cast<bf16x8*>(wB + 8) = pb1;
    __syncthreads();  // tiles visible

    bf16x8 afr[4], bfr[4];
#pragma unroll
    for (int mi = 0; mi < 4; ++mi)
      afr[mi] = *reinterpret_cast<const bf16x8*>(&ldsA[(wr * 64 + mi * 16 + lrow) * LDK + ko * 8]);
#pragma unroll
    for (int ni = 0; ni < 4; ++ni)
      bfr[ni] = *reinterpret_cast<const bf16x8*>(&ldsB[(wc * 64 + ni * 16 + lrow) * LDK + ko * 8]);
#pragma unroll
    for (int mi = 0; mi < 4; ++mi)
#pragma unroll
      for (int ni = 0; ni < 4; ++ni)
        acc[mi][ni] = __builtin_amdgcn_mfma_f32_16x16x32_bf16(afr[mi], bfr[ni], acc[mi][ni], 0, 0, 0);
  }

  // ---------- epilogue: tanh, weight by v, row-reduce, atomicAdd ----------
  // C/D layout (m89-verified): col = lane&15, row = (lane>>4)*4 + reg
#pragma unroll
  for (int mi = 0; mi < 4; ++mi) {
#pragma unroll
    for (int r = 0; r < 4; ++r) {
      float partial = 0.f;
#pragma unroll
      for (int ni = 0; ni < 4; ++ni) {
        int col = wc * 64 + ni * 16 + lrow;
        float x = acc[mi][ni][r] + sm_w1q[col];
        float e = __expf(2.f * x);
        float th = 1.f - 2.f / (e + 1.f);   // tanh(x); saturates correctly at +-inf
        partial += th * sm_v[col];
      }
      // reduce across the 16 lanes (lrow) that share this output row
      partial += __shfl_xor(partial, 1);
      partial += __shfl_xor(partial, 2);
      partial += __shfl_xor(partial, 4);
      partial += __shfl_xor(partial, 8);
      if (lrow == 0) {
        atomicAdd(&scores[bs0 + wr * 64 + mi * 16 + ko * 4 + r], partial);
      }
    }
  }
}

// ---------------- Stage C: masked softmax over s per b ----------------
__global__ __launch_bounds__(256) void softmax_kernel(const float* __restrict__ scores,
                                                      const int* __restrict__ mask,
                                                      float* __restrict__ out) {
  const int b = blockIdx.x;
  const int t = threadIdx.x;
  float sc[8];
  float mx = -3.4e38f;
#pragma unroll
  for (int j = 0; j < 8; ++j) {
    int i = t + j * 256;
    float s = scores[b * NS + i];
    if (mask[b * NS + i] == 0) s -= MASK_NEG;
    sc[j] = s;
    mx = fmaxf(mx, s);
  }
#pragma unroll
  for (int off = 1; off < 64; off <<= 1) mx = fmaxf(mx, __shfl_xor(mx, off));
  __shared__ float redm[4];
  __shared__ float reds[4];
  if ((t & 63) == 0) redm[t >> 6] = mx;
  __syncthreads();
  mx = fmaxf(fmaxf(redm[0], redm[1]), fmaxf(redm[2], redm[3]));
  float e[8];
  float sum = 0.f;
#pragma unroll
  for (int j = 0; j < 8; ++j) {
    e[j] = __expf(sc[j] - mx);  // masked: exp(-1e30) -> 0
    sum += e[j];
  }
#pragma unroll
  for (int off = 1; off < 64; off <<= 1) sum += __shfl_xor(sum, off);
  if ((t & 63) == 0) reds[t >> 6] = sum;
  __syncthreads();
  sum = reds[0] + reds[1] + reds[2] + reds[3];
  float inv = 1.f / sum;
#pragma unroll
  for (int j = 0; j < 8; ++j) out[b * NS + t + j * 256] = e[j] * inv;
}

extern "C" void kernel_launch(void* const* d_in, const int* in_sizes, int n_in,
                              void* d_out, int out_size, void* d_ws, size_t ws_size,
                              hipStream_t stream) {
  const float* q = (const float*)d_in[0];
  const float* keys = (const float*)d_in[1];
  const int* mask = (const int*)d_in[2];
  const float* W1 = (const float*)d_in[3];
  const float* W2 = (const float*)d_in[4];
  const float* v = (const float*)d_in[5];
  float* out = (float*)d_out;

  float* scores = (float*)d_ws;          // NB*NS fp32
  float* w1q = scores + NB * NS;         // NB*NA fp32

  zero_f32<<<(NB * NS + 255) / 256, 256, 0, stream>>>(scores, NB * NS);
  w1q_kernel<<<dim3(NA / 64, NB), 256, 0, stream>>>(q, W1, w1q);
  score_gemm<<<dim3(NA / BN, NB * NS / BM), 256, 0, stream>>>(keys, W2, w1q, v, scores);
  softmax_kernel<<<NB, 256, 0, stream>>>(scores, mask, out);
}

// Round 2
// 308.360 us; speedup vs baseline: 1.2147x; 1.2147x over previous
//
#include <hip/hip_runtime.h>
#include <hip/hip_bf16.h>
#include <stdint.h>

#define NB 32
#define NS 2048
#define ND 1024
#define NA 1024
#define MASK_NEG 1e30f

#define BM 128   // bs rows per block
#define BN 128   // a cols per nt-tile
#define BK 64    // K-step
#define NT (NA / BN)
#define KSTEPS (ND / BK)

typedef __attribute__((ext_vector_type(4))) float f32x4;
typedef __attribute__((ext_vector_type(8))) __bf16 bf16x8;

__device__ __forceinline__ void glds16(const void* g, void* l) {
  __builtin_amdgcn_global_load_lds(
      (const __attribute__((address_space(1))) uint32_t*)g,
      (__attribute__((address_space(3))) uint32_t*)(uintptr_t)l, 16, 0, 0);
}

// ---------------- fp32 -> bf16 bulk convert ----------------
__global__ __launch_bounds__(256) void cvt_bf16(const float* __restrict__ in,
                                                __bf16* __restrict__ out, int n8) {
  long i = blockIdx.x * 256 + threadIdx.x;
  const long stride = (long)gridDim.x * 256;
  for (; i < n8; i += stride) {
    f32x4 a = ((const f32x4*)in)[2 * i];
    f32x4 b = ((const f32x4*)in)[2 * i + 1];
    bf16x8 o;
#pragma unroll
    for (int j = 0; j < 4; ++j) { o[j] = (__bf16)a[j]; o[4 + j] = (__bf16)b[j]; }
    ((bf16x8*)out)[i] = o;
  }
}

// ---------------- w1q[b,a] = query[b,:] . W1[a,:]  (fp32) ----------------
__global__ __launch_bounds__(256) void w1q_kernel(const float* __restrict__ q,
                                                  const float* __restrict__ W1,
                                                  float* __restrict__ w1q) {
  const int b = blockIdx.y;
  const int a0 = blockIdx.x * 64;
  const int t = threadIdx.x;
  const int al = t >> 2;
  const int part = t & 3;
  const float* wrow = W1 + (size_t)(a0 + al) * ND + part * 256;
  const float* qrow = q + (size_t)b * ND + part * 256;
  float sum = 0.f;
#pragma unroll 8
  for (int i = 0; i < 256; i += 4) {
    float4 w = *reinterpret_cast<const float4*>(wrow + i);
    float4 x = *reinterpret_cast<const float4*>(qrow + i);
    sum += w.x * x.x + w.y * x.y + w.z * x.z + w.w * x.w;
  }
  __shared__ float red[256];
  red[t] = sum;
  __syncthreads();
  if (t < 64) {
    w1q[(size_t)b * NA + a0 + t] = red[t * 4] + red[t * 4 + 1] + red[t * 4 + 2] + red[t * 4 + 3];
  }
}

// ---------------- fused scores GEMM ----------------
// Block: 128 bs-rows x full A. For each nt (8 a-tiles of 128): K-loop MFMA,
// epilogue tanh + v-weight accumulated into regs; final LDS cross-wave reduce,
// direct store of scores (no atomics).
// LDS layout (both tiles): row-major [128][BK] bf16, 128 B/row = 8 slots of 16B,
// XOR-swizzled: slot_stored = col16 ^ (row & 7). global_load_lds writes linearly,
// so the *source* address is inverse-permuted (same involution).
template <bool APRE>
__global__ __launch_bounds__(256, 2) void score_gemm2(
    const float* __restrict__ keysf,   // fp32 keys (fallback path)
    const __bf16* __restrict__ keysb,  // bf16 keys (APRE path)
    const __bf16* __restrict__ W2b,    // bf16 W2 (always)
    const float* __restrict__ w1q,
    const float* __restrict__ vvec,
    float* __restrict__ scores) {
  __shared__ __bf16 ldsA[BM * BK];   // 16 KB
  __shared__ __bf16 ldsB[BN * BK];   // 16 KB
  __shared__ float sm_w1q[NA];       // 4 KB
  __shared__ float sm_v[NA];         // 4 KB
  __shared__ float sm_part[2][BM];   // 1 KB

  const int t = threadIdx.x;
  const int bs0 = blockIdx.x * BM;
  const int b = bs0 / NS;

#pragma unroll
  for (int i = t; i < NA; i += 256) {
    sm_w1q[i] = w1q[(size_t)b * NA + i];
    sm_v[i] = vvec[i];
  }

  const int lane = t & 63;
  const int wid = t >> 6;
  const int wr = wid >> 1, wc = wid & 1;
  const int lrow = lane & 15, ko = lane >> 4;

  // glds staging geometry: chunk = 1 KB = 8 rows of 128 B; wave w owns chunks 4w..4w+3.
  // lane l: row-in-chunk = l>>3, slot = l&7 -> logical col16 = (l&7) ^ (l>>3).
  const int srow = lane >> 3;
  const int scol16 = (lane & 7) ^ srow;

  const __bf16* gA[4];
  const __bf16* gB[4];
#pragma unroll
  for (int j = 0; j < 4; ++j) {
    const int c = wid * 4 + j;
    gA[j] = keysb + (size_t)(bs0 + c * 8 + srow) * ND + scol16 * 8;
    gB[j] = W2b + (size_t)(c * 8 + srow) * ND + scol16 * 8;
  }

  // reg-staging geometry (fallback): thread t -> row r = t>>1, 4 slots per thread
  const int rr = t >> 1;
  const int rhalf = t & 1;
  const float* gAf = keysf + (size_t)(bs0 + rr) * ND;

  float part[4][4] = {};

  for (int nt = 0; nt < NT; ++nt) {
    const int a0 = nt * BN;
    f32x4 acc[4][4];
#pragma unroll
    for (int i = 0; i < 4; ++i)
#pragma unroll
      for (int j = 0; j < 4; ++j) acc[i][j] = f32x4{0.f, 0.f, 0.f, 0.f};

    for (int ks = 0; ks < KSTEPS; ++ks) {
      const int k0 = ks * BK;
      // ---- stage B (always glds) ----
#pragma unroll
      for (int j = 0; j < 4; ++j) {
        glds16(gB[j] + (size_t)a0 * ND + k0, (char*)ldsB + (wid * 4 + j) * 1024);
      }
      // ---- stage A ----
      if constexpr (APRE) {
#pragma unroll
        for (int j = 0; j < 4; ++j) {
          glds16(gA[j] + k0, (char*)ldsA + (wid * 4 + j) * 1024);
        }
      } else {
#pragma unroll
        for (int s = 0; s < 4; ++s) {
          const int slot = rhalf * 4 + s;
          const int col16 = slot ^ (rr & 7);
          const float* gp = gAf + k0 + col16 * 8;
          float4 x0 = *reinterpret_cast<const float4*>(gp);
          float4 x1 = *reinterpret_cast<const float4*>(gp + 4);
          bf16x8 o;
          o[0] = (__bf16)x0.x; o[1] = (__bf16)x0.y; o[2] = (__bf16)x0.z; o[3] = (__bf16)x0.w;
          o[4] = (__bf16)x1.x; o[5] = (__bf16)x1.y; o[6] = (__bf16)x1.z; o[7] = (__bf16)x1.w;
          *reinterpret_cast<bf16x8*>((char*)ldsA + rr * 128 + slot * 16) = o;
        }
      }
      __syncthreads();  // staging visible (compiler drains vmcnt/lgkmcnt)

      // ---- fragments (swizzled read) ----
      bf16x8 afr[4][2], bfr[4][2];
#pragma unroll
      for (int mi = 0; mi < 4; ++mi) {
        const int ra = wr * 64 + mi * 16 + lrow;
#pragma unroll
        for (int kk = 0; kk < 2; ++kk) {
          const int slot = (kk * 4 + ko) ^ (ra & 7);
          afr[mi][kk] = *reinterpret_cast<const bf16x8*>((const char*)ldsA + ra * 128 + slot * 16);
        }
      }
#pragma unroll
      for (int ni = 0; ni < 4; ++ni) {
        const int rb = wc * 64 + ni * 16 + lrow;
#pragma unroll
        for (int kk = 0; kk < 2; ++kk) {
          const int slot = (kk * 4 + ko) ^ (rb & 7);
          bfr[ni][kk] = *reinterpret_cast<const bf16x8*>((const char*)ldsB + rb * 128 + slot * 16);
        }
      }
#pragma unroll
      for (int mi = 0; mi < 4; ++mi)
#pragma unroll
        for (int ni = 0; ni < 4; ++ni)
#pragma unroll
          for (int kk = 0; kk < 2; ++kk)
            acc[mi][ni] = __builtin_amdgcn_mfma_f32_16x16x32_bf16(afr[mi][kk], bfr[ni][kk],
                                                                  acc[mi][ni], 0, 0, 0);
      __syncthreads();  // fragment reads done before next stage overwrites
    }

    // ---- per-nt epilogue: tanh + v-weight into register partials ----
    // C/D layout: col = lane&15 (=lrow), row = ko*4 + r
#pragma unroll
    for (int mi = 0; mi < 4; ++mi)
#pragma unroll
      for (int r = 0; r < 4; ++r) {
        float p = 0.f;
#pragma unroll
        for (int ni = 0; ni < 4; ++ni) {
          const int a = a0 + wc * 64 + ni * 16 + lrow;
          const float x = acc[mi][ni][r] + sm_w1q[a];
          const float e = __expf(2.f * x);
          p += (1.f - 2.f / (e + 1.f)) * sm_v[a];
        }
        part[mi][r] += p;
      }
  }

  // ---- final reduce: 16 lanes (lrow) -> LDS -> combine wc halves ----
#pragma unroll
  for (int mi = 0; mi < 4; ++mi)
#pragma unroll
    for (int r = 0; r < 4; ++r) {
      float p = part[mi][r];
      p += __shfl_xor(p, 1);
      p += __shfl_xor(p, 2);
      p += __shfl_xor(p, 4);
      p += __shfl_xor(p, 8);
      if (lrow == 0) sm_part[wc][wr * 64 + mi * 16 + ko * 4 + r] = p;
    }
  __syncthreads();
  if (t < BM) scores[bs0 + t] = sm_part[0][t] + sm_part[1][t];
}

// ---------------- masked softmax ----------------
__global__ __launch_bounds__(256) void softmax_kernel(const float* __restrict__ scores,
                                                      const int* __restrict__ mask,
                                                      float* __restrict__ out) {
  const int b = blockIdx.x;
  const int t = threadIdx.x;
  float sc[8];
  float mx = -3.4e38f;
#pragma unroll
  for (int j = 0; j < 8; ++j) {
    int i = t + j * 256;
    float s = scores[b * NS + i];
    if (mask[b * NS + i] == 0) s -= MASK_NEG;
    sc[j] = s;
    mx = fmaxf(mx, s);
  }
#pragma unroll
  for (int off = 1; off < 64; off <<= 1) mx = fmaxf(mx, __shfl_xor(mx, off));
  __shared__ float redm[4];
  __shared__ float reds[4];
  if ((t & 63) == 0) redm[t >> 6] = mx;
  __syncthreads();
  mx = fmaxf(fmaxf(redm[0], redm[1]), fmaxf(redm[2], redm[3]));
  float e[8];
  float sum = 0.f;
#pragma unroll
  for (int j = 0; j < 8; ++j) {
    e[j] = __expf(sc[j] - mx);
    sum += e[j];
  }
#pragma unroll
  for (int off = 1; off < 64; off <<= 1) sum += __shfl_xor(sum, off);
  if ((t & 63) == 0) reds[t >> 6] = sum;
  __syncthreads();
  sum = reds[0] + reds[1] + reds[2] + reds[3];
  float inv = 1.f / sum;
#pragma unroll
  for (int j = 0; j < 8; ++j) out[b * NS + t + j * 256] = e[j] * inv;
}

extern "C" void kernel_launch(void* const* d_in, const int* in_sizes, int n_in,
                              void* d_out, int out_size, void* d_ws, size_t ws_size,
                              hipStream_t stream) {
  const float* q = (const float*)d_in[0];
  const float* keysf = (const float*)d_in[1];
  const int* mask = (const int*)d_in[2];
  const float* W1 = (const float*)d_in[3];
  const float* W2f = (const float*)d_in[4];
  const float* v = (const float*)d_in[5];
  float* out = (float*)d_out;

  // ws layout (16B-aligned sections)
  float* scores = (float*)d_ws;                              // 256 KB
  float* w1q = scores + NB * NS;                             // 128 KB
  __bf16* W2b = (__bf16*)(w1q + NB * NA);                    // 2 MB
  __bf16* keysb = (__bf16*)((char*)W2b + (size_t)NA * ND * 2);  // 128 MB
  const size_t need = (size_t)NB * NS * 4 + (size_t)NB * NA * 4 +
                      (size_t)NA * ND * 2 + (size_t)NB * NS * ND * 2;
  const bool apre = ws_size >= need;

  cvt_bf16<<<512, 256, 0, stream>>>(W2f, W2b, NA * ND / 8);
  if (apre) cvt_bf16<<<2048, 256, 0, stream>>>(keysf, keysb, (int)((size_t)NB * NS * ND / 8));
  w1q_kernel<<<dim3(NA / 64, NB), 256, 0, stream>>>(q, W1, w1q);
  if (apre)
    score_gemm2<true><<<NB * NS / BM, 256, 0, stream>>>(keysf, keysb, W2b, w1q, v, scores);
  else
    score_gemm2<false><<<NB * NS / BM, 256, 0, stream>>>(keysf, keysb, W2b, w1q, v, scores);
  softmax_kernel<<<NB, 256, 0, stream>>>(scores, mask, out);
}

// Round 4
// 269.729 us; speedup vs baseline: 1.3887x; 1.1432x over previous
//
#include <hip/hip_runtime.h>
#include <hip/hip_bf16.h>
#include <stdint.h>

#define NB 32
#define NS 2048
#define ND 1024
#define NA 1024
#define MASK_NEG 1e30f

#define BM 256
#define BN 256
#define BK 64
#define NTL (NA / BN)        // 4 a-tiles
#define KT (ND / BK)         // 16 K-tiles per a-tile
#define TT_TOTAL (NTL * KT)  // 64

typedef __attribute__((ext_vector_type(4))) float f32x4;
typedef __attribute__((ext_vector_type(8))) __bf16 bf16x8;

__device__ __forceinline__ void glds16(const void* g, void* l) {
  __builtin_amdgcn_global_load_lds(
      (const __attribute__((address_space(1))) uint32_t*)g,
      (__attribute__((address_space(3))) uint32_t*)(uintptr_t)l, 16, 0, 0);
}

// ---------------- fp32 -> bf16 bulk convert ----------------
__global__ __launch_bounds__(256) void cvt_bf16(const float* __restrict__ in,
                                                __bf16* __restrict__ out, int n8) {
  long i = blockIdx.x * 256 + threadIdx.x;
  const long stride = (long)gridDim.x * 256;
  for (; i < n8; i += stride) {
    f32x4 a = ((const f32x4*)in)[2 * i];
    f32x4 b = ((const f32x4*)in)[2 * i + 1];
    bf16x8 o;
#pragma unroll
    for (int j = 0; j < 4; ++j) { o[j] = (__bf16)a[j]; o[4 + j] = (__bf16)b[j]; }
    ((bf16x8*)out)[i] = o;
  }
}

// ---------------- w1q[b,a] = query[b,:] . W1[a,:]  (fp32) ----------------
__global__ __launch_bounds__(256) void w1q_kernel(const float* __restrict__ q,
                                                  const float* __restrict__ W1,
                                                  float* __restrict__ w1q) {
  const int b = blockIdx.x;          // b-major: W1 slice shared within XCD round-robin
  const int a0 = blockIdx.y * 64;
  const int t = threadIdx.x;
  const int al = t >> 2;
  const int part = t & 3;
  const float* wrow = W1 + (size_t)(a0 + al) * ND + part * 256;
  const float* qrow = q + (size_t)b * ND + part * 256;
  float sum = 0.f;
#pragma unroll 8
  for (int i = 0; i < 256; i += 4) {
    float4 w = *reinterpret_cast<const float4*>(wrow + i);
    float4 x = *reinterpret_cast<const float4*>(qrow + i);
    sum += w.x * x.x + w.y * x.y + w.z * x.z + w.w * x.w;
  }
  __shared__ float red[256];
  red[t] = sum;
  __syncthreads();
  if (t < 64) {
    w1q[(size_t)b * NA + a0 + t] = red[t * 4] + red[t * 4 + 1] + red[t * 4 + 2] + red[t * 4 + 3];
  }
}

// ---------------- fused scores GEMM, 4-phase pipelined ----------------
// LDS tile layout (A and B): row-major [rows][64] bf16, 128 B/row = 8 slots
// of 16 B, XOR-swizzled: stored_slot = col16 ^ (row & 7). global_load_lds
// writes linearly, so the global source address carries the inverse
// permutation (same involution). Verified 0 bank conflicts in R2.
__global__ __launch_bounds__(512, 1) void score_gemm8(
    const __bf16* __restrict__ keysb, const __bf16* __restrict__ W2b,
    const float* __restrict__ w1q, const float* __restrict__ vvec,
    float* __restrict__ scores) {
  __shared__ __bf16 Ab[2][BM * BK];   // 2 x 32 KB
  __shared__ __bf16 Bb[2][BN * BK];   // 2 x 32 KB
  __shared__ float sm_w1q[NA];        // 4 KB
  __shared__ float sm_v[NA];          // 4 KB
  __shared__ float sm_part[4][BM];    // 4 KB

  const int t = threadIdx.x;
  const int bs0 = blockIdx.x * BM;
  const int b = bs0 >> 11;  // / NS; 8 blocks per b, no straddle
  const int lane = t & 63;
  const int wid = t >> 6;
  const int wr = wid >> 2;  // 0..1 -> 128-row half
  const int wc = wid & 3;   // 0..3 -> 64-col quarter
  const int lrow = lane & 15;
  const int ko = lane >> 4;

  for (int i = t; i < NA; i += 512) {
    sm_w1q[i] = w1q[(size_t)b * NA + i];
    sm_v[i] = vvec[i];
  }
  for (int i = t; i < 4 * BM; i += 512) ((float*)sm_part)[i] = 0.f;

  // staging lane geometry: chunk = 1 KB = 8 rows; round r -> chunk r*8+wid
  const int srow = lane >> 3;
  const int scol = (lane & 7) ^ srow;  // logical col16 this lane must fetch
  size_t aoffg[4], boffg[4];
#pragma unroll
  for (int r = 0; r < 4; ++r) {
    const int row = (r * 8 + wid) * 8 + srow;
    aoffg[r] = (size_t)(bs0 + row) * ND + scol * 8;
    boffg[r] = (size_t)row * ND + scol * 8;
  }
  const int ldsoff = wid * 1024;

  // fragment k-slot (pre-swizzle): col16 = kk*4+ko, row&7 == lrow&7
  const int sl0 = ko ^ (lrow & 7);
  const int sl1 = (4 + ko) ^ (lrow & 7);

  f32x4 acc[8][4];
#pragma unroll
  for (int mi = 0; mi < 8; ++mi)
#pragma unroll
    for (int ni = 0; ni < 4; ++ni) acc[mi][ni] = f32x4{0.f, 0.f, 0.f, 0.f};

  // ---- prologue: stage tile 0 into buf 0 ----
#pragma unroll
  for (int r = 0; r < 4; ++r) {
    glds16(keysb + aoffg[r], (char*)Ab[0] + ldsoff + r * 8192);
    glds16(W2b + boffg[r], (char*)Bb[0] + ldsoff + r * 8192);
  }
  __syncthreads();

  for (int tt = 0; tt < TT_TOTAL; ++tt) {
    const int c = tt & 1;
    const char* Ac = (const char*)Ab[c];
    const char* Bc = (const char*)Bb[c];
    char* An = (char*)Ab[c ^ 1];
    char* Bn = (char*)Bb[c ^ 1];
    const int ntt = tt + 1;
    const bool hn = ntt < TT_TOTAL;
    const size_t akoff = (size_t)((ntt & 15) * BK);
    const size_t bkoff = (size_t)((ntt >> 4) * BN) * ND + (size_t)((ntt & 15) * BK);

    bf16x8 bfr[4][2], af[4][2];

    // ======== phase 1: stage A0,A1 | read bfr[0..1], af(mi 0-3) | mfma ========
    if (hn) {
      glds16(keysb + aoffg[0] + akoff, An + ldsoff);
      glds16(keysb + aoffg[1] + akoff, An + ldsoff + 8192);
    }
#pragma unroll
    for (int ni = 0; ni < 2; ++ni) {
      const int rb = (wc * 64 + ni * 16 + lrow) * 128;
      bfr[ni][0] = *reinterpret_cast<const bf16x8*>(Bc + rb + sl0 * 16);
      bfr[ni][1] = *reinterpret_cast<const bf16x8*>(Bc + rb + sl1 * 16);
    }
#pragma unroll
    for (int mi = 0; mi < 4; ++mi) {
      const int ra = (wr * 128 + mi * 16 + lrow) * 128;
      af[mi][0] = *reinterpret_cast<const bf16x8*>(Ac + ra + sl0 * 16);
      af[mi][1] = *reinterpret_cast<const bf16x8*>(Ac + ra + sl1 * 16);
    }
    __builtin_amdgcn_s_barrier();
    asm volatile("s_waitcnt lgkmcnt(0)" ::: "memory");
    __builtin_amdgcn_sched_barrier(0);
    __builtin_amdgcn_s_setprio(1);
#pragma unroll
    for (int mi = 0; mi < 4; ++mi)
#pragma unroll
      for (int ni = 0; ni < 2; ++ni) {
        acc[mi][ni] = __builtin_amdgcn_mfma_f32_16x16x32_bf16(af[mi][0], bfr[ni][0], acc[mi][ni], 0, 0, 0);
        acc[mi][ni] = __builtin_amdgcn_mfma_f32_16x16x32_bf16(af[mi][1], bfr[ni][1], acc[mi][ni], 0, 0, 0);
      }
    __builtin_amdgcn_s_setprio(0);
    __builtin_amdgcn_s_barrier();

    // ======== phase 2: stage A2,A3 | read bfr[2..3] | mfma mi0-3 x ni2-3 ========
    if (hn) {
      glds16(keysb + aoffg[2] + akoff, An + ldsoff + 2 * 8192);
      glds16(keysb + aoffg[3] + akoff, An + ldsoff + 3 * 8192);
    }
#pragma unroll
    for (int ni = 2; ni < 4; ++ni) {
      const int rb = (wc * 64 + ni * 16 + lrow) * 128;
      bfr[ni][0] = *reinterpret_cast<const bf16x8*>(Bc + rb + sl0 * 16);
      bfr[ni][1] = *reinterpret_cast<const bf16x8*>(Bc + rb + sl1 * 16);
    }
    __builtin_amdgcn_s_barrier();
    asm volatile("s_waitcnt lgkmcnt(0)" ::: "memory");
    __builtin_amdgcn_sched_barrier(0);
    __builtin_amdgcn_s_setprio(1);
#pragma unroll
    for (int mi = 0; mi < 4; ++mi)
#pragma unroll
      for (int ni = 2; ni < 4; ++ni) {
        acc[mi][ni] = __builtin_amdgcn_mfma_f32_16x16x32_bf16(af[mi][0], bfr[ni][0], acc[mi][ni], 0, 0, 0);
        acc[mi][ni] = __builtin_amdgcn_mfma_f32_16x16x32_bf16(af[mi][1], bfr[ni][1], acc[mi][ni], 0, 0, 0);
      }
    __builtin_amdgcn_s_setprio(0);
    __builtin_amdgcn_s_barrier();

    // ======== phase 3: stage B0,B1 | read af(mi 4-7) | mfma mi4-7 x ni0-1 ========
    if (hn) {
      glds16(W2b + boffg[0] + bkoff, Bn + ldsoff);
      glds16(W2b + boffg[1] + bkoff, Bn + ldsoff + 8192);
    }
#pragma unroll
    for (int mi = 0; mi < 4; ++mi) {
      const int ra = (wr * 128 + 64 + mi * 16 + lrow) * 128;
      af[mi][0] = *reinterpret_cast<const bf16x8*>(Ac + ra + sl0 * 16);
      af[mi][1] = *reinterpret_cast<const bf16x8*>(Ac + ra + sl1 * 16);
    }
    __builtin_amdgcn_s_barrier();
    asm volatile("s_waitcnt lgkmcnt(0)" ::: "memory");
    __builtin_amdgcn_sched_barrier(0);
    __builtin_amdgcn_s_setprio(1);
#pragma unroll
    for (int mi = 0; mi < 4; ++mi)
#pragma unroll
      for (int ni = 0; ni < 2; ++ni) {
        acc[4 + mi][ni] = __builtin_amdgcn_mfma_f32_16x16x32_bf16(af[mi][0], bfr[ni][0], acc[4 + mi][ni], 0, 0, 0);
        acc[4 + mi][ni] = __builtin_amdgcn_mfma_f32_16x16x32_bf16(af[mi][1], bfr[ni][1], acc[4 + mi][ni], 0, 0, 0);
      }
    __builtin_amdgcn_s_setprio(0);
    __builtin_amdgcn_s_barrier();

    // ======== phase 4: stage B2,B3 | mfma mi4-7 x ni2-3 | vmcnt drain ========
    if (hn) {
      glds16(W2b + boffg[2] + bkoff, Bn + ldsoff + 2 * 8192);
      glds16(W2b + boffg[3] + bkoff, Bn + ldsoff + 3 * 8192);
    }
    __builtin_amdgcn_s_setprio(1);
#pragma unroll
    for (int mi = 0; mi < 4; ++mi)
#pragma unroll
      for (int ni = 2; ni < 4; ++ni) {
        acc[4 + mi][ni] = __builtin_amdgcn_mfma_f32_16x16x32_bf16(af[mi][0], bfr[ni][0], acc[4 + mi][ni], 0, 0, 0);
        acc[4 + mi][ni] = __builtin_amdgcn_mfma_f32_16x16x32_bf16(af[mi][1], bfr[ni][1], acc[4 + mi][ni], 0, 0, 0);
      }
    __builtin_amdgcn_s_setprio(0);
    asm volatile("s_waitcnt vmcnt(0)" ::: "memory");
    __builtin_amdgcn_s_barrier();

    // ======== per-a-tile epilogue: tanh + v-weight -> sm_part ========
    if ((tt & 15) == 15) {
      const int a0 = (tt >> 4) * BN;
      float w1v[4], vv[4];
#pragma unroll
      for (int ni = 0; ni < 4; ++ni) {
        const int a = a0 + wc * 64 + ni * 16 + lrow;
        w1v[ni] = sm_w1q[a];
        vv[ni] = sm_v[a];
      }
#pragma unroll
      for (int mi = 0; mi < 8; ++mi)
#pragma unroll
        for (int r = 0; r < 4; ++r) {
          float p = 0.f;
#pragma unroll
          for (int ni = 0; ni < 4; ++ni) {
            const float x = acc[mi][ni][r] + w1v[ni];
            const float e = __expf(2.f * x);
            p += (1.f - 2.f * __builtin_amdgcn_rcpf(e + 1.f)) * vv[ni];
          }
          p += __shfl_xor(p, 1);
          p += __shfl_xor(p, 2);
          p += __shfl_xor(p, 4);
          p += __shfl_xor(p, 8);
          if (lrow == 0) sm_part[wc][wr * 128 + mi * 16 + ko * 4 + r] += p;
        }
#pragma unroll
      for (int mi = 0; mi < 8; ++mi)
#pragma unroll
        for (int ni = 0; ni < 4; ++ni) acc[mi][ni] = f32x4{0.f, 0.f, 0.f, 0.f};
    }
  }

  __syncthreads();
  if (t < BM)
    scores[bs0 + t] = sm_part[0][t] + sm_part[1][t] + sm_part[2][t] + sm_part[3][t];
}

// ---------------- masked softmax ----------------
__global__ __launch_bounds__(256) void softmax_kernel(const float* __restrict__ scores,
                                                      const int* __restrict__ mask,
                                                      float* __restrict__ out) {
  const int b = blockIdx.x;
  const int t = threadIdx.x;
  float sc[8];
  float mx = -3.4e38f;
#pragma unroll
  for (int j = 0; j < 8; ++j) {
    int i = t + j * 256;
    float s = scores[b * NS + i];
    if (mask[b * NS + i] == 0) s -= MASK_NEG;
    sc[j] = s;
    mx = fmaxf(mx, s);
  }
#pragma unroll
  for (int off = 1; off < 64; off <<= 1) mx = fmaxf(mx, __shfl_xor(mx, off));
  __shared__ float redm[4];
  __shared__ float reds[4];
  if ((t & 63) == 0) redm[t >> 6] = mx;
  __syncthreads();
  mx = fmaxf(fmaxf(redm[0], redm[1]), fmaxf(redm[2], redm[3]));
  float e[8];
  float sum = 0.f;
#pragma unroll
  for (int j = 0; j < 8; ++j) {
    e[j] = __expf(sc[j] - mx);
    sum += e[j];
  }
#pragma unroll
  for (int off = 1; off < 64; off <<= 1) sum += __shfl_xor(sum, off);
  if ((t & 63) == 0) reds[t >> 6] = sum;
  __syncthreads();
  sum = reds[0] + reds[1] + reds[2] + reds[3];
  float inv = 1.f / sum;
#pragma unroll
  for (int j = 0; j < 8; ++j) out[b * NS + t + j * 256] = e[j] * inv;
}

extern "C" void kernel_launch(void* const* d_in, const int* in_sizes, int n_in,
                              void* d_out, int out_size, void* d_ws, size_t ws_size,
                              hipStream_t stream) {
  const float* q = (const float*)d_in[0];
  const float* keysf = (const float*)d_in[1];
  const int* mask = (const int*)d_in[2];
  const float* W1 = (const float*)d_in[3];
  const float* W2f = (const float*)d_in[4];
  const float* v = (const float*)d_in[5];
  float* out = (float*)d_out;

  float* scores = (float*)d_ws;                                 // 256 KB
  float* w1q = scores + NB * NS;                                // 128 KB
  __bf16* W2b = (__bf16*)(w1q + NB * NA);                       // 2 MB
  __bf16* keysb = (__bf16*)((char*)W2b + (size_t)NA * ND * 2);  // 128 MB

  cvt_bf16<<<512, 256, 0, stream>>>(W2f, W2b, NA * ND / 8);
  cvt_bf16<<<2048, 256, 0, stream>>>(keysf, keysb, (int)((size_t)NB * NS * ND / 8));
  w1q_kernel<<<dim3(NB, NA / 64), 256, 0, stream>>>(q, W1, w1q);
  score_gemm8<<<NB * NS / BM, 512, 0, stream>>>(keysb, W2b, w1q, v, scores);
  softmax_kernel<<<NB, 256, 0, stream>>>(scores, mask, out);
}